// Round 17
// baseline (457.068 us; speedup 1.0000x reference)
//
#include <hip/hip_runtime.h>
#include <hip/hip_bf16.h>
#include <math.h>

#define T_TOKENS 4096
#define DMODEL 1024
#define DFF 4096
#define NEXP 24
#define NSLOTS 8192
#define BKP 40   // Bs row stride in shorts (80B, 16B-aligned)

typedef __attribute__((ext_vector_type(8))) short bf16x8;
typedef __attribute__((ext_vector_type(4))) float f32x4;
typedef __attribute__((ext_vector_type(8))) unsigned short us8;

static __device__ __forceinline__ unsigned short f2bf(float f) {
    union { float f; unsigned u; } v; v.f = f;
    unsigned r = v.u + 0x7fffu + ((v.u >> 16) & 1u);
    return (unsigned short)(r >> 16);
}

typedef const __attribute__((address_space(1))) void gvoid_t;
typedef __attribute__((address_space(3))) void lvoid_t;
static __device__ __forceinline__ void gl_lds16(const void* g, void* l) {
    __builtin_amdgcn_global_load_lds((gvoid_t*)g, (lvoid_t*)l, 16, 0, 0);
}

// ---------------- zero the control block ----------------
__global__ void k_zero(int* __restrict__ p) { p[threadIdx.x] = 0; }

// ---------------- gating: block = 8 tokens x 32 lanes (lane = expert) --------
__global__ __launch_bounds__(256) void k_gate(
    const float* __restrict__ x, const float* __restrict__ gw,
    const float* __restrict__ gb, int* __restrict__ topk_e,
    float* __restrict__ topk_g, int* __restrict__ counts)
{
    __shared__ float xs[8][1024];
    __shared__ float sc[8][24];
    __shared__ int lcnt[24];
    int tid = threadIdx.x;
    int t0 = blockIdx.x * 8;
    #pragma unroll
    for (int i = 0; i < 8; i++) {
        int idx = tid + 256*i;
        int r = idx >> 8, c4 = (idx & 255) * 4;
        *(float4*)&xs[r][c4] = *(const float4*)(x + (size_t)(t0+r)*DMODEL + c4);
    }
    if (tid < 24) lcnt[tid] = 0;
    __syncthreads();

    int tok = tid >> 5, e = tid & 31;
    if (e < NEXP) {
        float s0=0.f, s1=0.f, s2=0.f, s3=0.f;
        #pragma unroll 4
        for (int d = 0; d < DMODEL; d += 4) {
            s0 += xs[tok][d]   * gw[(d  )*NEXP + e];
            s1 += xs[tok][d+1] * gw[(d+1)*NEXP + e];
            s2 += xs[tok][d+2] * gw[(d+2)*NEXP + e];
            s3 += xs[tok][d+3] * gw[(d+3)*NEXP + e];
        }
        sc[tok][e] = (s0+s1)+(s2+s3) + gb[e];
    }
    __syncthreads();

    if (tid < 8) {
        int t = t0 + tid;
        float v0=-1e30f, v1=-1e30f; int i0=0, i1=0;
        #pragma unroll
        for (int ee = 0; ee < NEXP; ee++) {
            float s = sc[tid][ee];
            if (s > v0) { v1=v0; i1=i0; v0=s; i0=ee; }
            else if (s > v1) { v1=s; i1=ee; }
        }
        float e1 = expf(v1 - v0);
        float g0 = 1.f/(1.f+e1), g1 = e1/(1.f+e1);
        topk_e[t*2]=i0; topk_e[t*2+1]=i1;
        topk_g[t*2]=g0; topk_g[t*2+1]=g1;
        atomicAdd(&lcnt[i0], 1); atomicAdd(&lcnt[i1], 1);
    }
    __syncthreads();
    if (tid < NEXP && lcnt[tid]) atomicAdd(&counts[tid], lcnt[tid]);
}

__global__ void k_scan(const int* __restrict__ counts, int* __restrict__ offsets) {
    if (threadIdx.x == 0) {
        int run = 0;
        for (int e = 0; e < NEXP; e++) { offsets[e] = run; run += counts[e]; }
        offsets[NEXP] = run;
    }
}

__global__ __launch_bounds__(256) void k_assign(
    const int* __restrict__ topk_e, const float* __restrict__ topk_g,
    const int* __restrict__ offsets, int* __restrict__ counts2,
    int* __restrict__ slot_token, float* __restrict__ slot_gate,
    int* __restrict__ slot_of)
{
    int idx = blockIdx.x * 256 + threadIdx.x;
    if (idx >= NSLOTS) return;
    int e = topk_e[idx];
    int pos = offsets[e] + atomicAdd(&counts2[e], 1);
    slot_token[pos] = idx >> 1;
    slot_gate[pos] = topk_g[idx];
    slot_of[idx] = pos;
}

// ---------------- gather x -> xg[slot][DMODEL] bf16 ----------------
__global__ __launch_bounds__(256) void k_xgather(
    const float* __restrict__ x, const int* __restrict__ slot_token,
    unsigned short* __restrict__ xg)
{
    int idx = blockIdx.x * 256 + threadIdx.x;
    int slot = idx >> 7, c8 = (idx & 127) * 8;
    int tok = slot_token[slot];
    const float4* p = (const float4*)(x + (size_t)tok * DMODEL + c8);
    float4 v0 = p[0], v1 = p[1];
    us8 o;
    o[0]=f2bf(v0.x); o[1]=f2bf(v0.y); o[2]=f2bf(v0.z); o[3]=f2bf(v0.w);
    o[4]=f2bf(v1.x); o[5]=f2bf(v1.y); o[6]=f2bf(v1.z); o[7]=f2bf(v1.w);
    *(us8*)(xg + (size_t)slot * DMODEL + c8) = o;
}

// ---------------- GEMM1: h = gelu(xg @ w1 + b1) ------------------------------
// M=256, N=128, BK=32, 512 thr. Issue-late ordering: next-tile loads issued
// AFTER barrier 1 (so barrier 1 drains nothing fresh) and covered by the
// compute phase before barrier 2's vmcnt(0) drain.
__global__ __launch_bounds__(512) void k_ffn1(
    const unsigned short* __restrict__ xg, const float* __restrict__ w1,
    const float* __restrict__ b1, const int* __restrict__ offsets,
    unsigned short* __restrict__ hbuf)
{
    int bid = blockIdx.x;
    int xcd = bid & 7, s = bid >> 3;           // s in [0,192)
    int eg = s >> 6, rem = s & 63;             // 64 = 32 nx * 2 mt
    int nx = rem >> 1, mt = rem & 1;
    int e = eg * 8 + xcd;

    int base = offsets[e], ne = offsets[e+1] - base;
    if (mt * 256 >= ne) return;
    int n0 = nx * 128;
    int slotbase = base + mt * 256;
    int mrows = ne - mt * 256;

    __shared__ unsigned short As[2][256*32];
    __shared__ unsigned short Bs[128*BKP];

    int tid = threadIdx.x, l = tid & 63, wv = tid >> 6;
    int wm = (wv >> 1) * 64, wn = (wv & 1) * 64;
    int lrow = l & 15, lkg = l >> 4;

    f32x4 acc[4][4];
    #pragma unroll
    for (int i = 0; i < 4; i++)
      #pragma unroll
      for (int j = 0; j < 4; j++)
        acc[i][j] = (f32x4){0.f, 0.f, 0.f, 0.f};

    const unsigned short* xga = xg + (size_t)slotbase * DMODEL;
    const float* w1e = w1 + (size_t)e * DMODEL * DFF + n0;

    int n4 = (tid & 31) * 4, kb = (tid >> 5) * 2;   // 2k x 4n block per thread
    float4 r0, r1;
    auto issueB = [&](int t) {
        const float* p = w1e + (size_t)(t*32 + kb) * DFF + n4;
        r0 = *(const float4*)p;
        r1 = *(const float4*)(p + DFF);
    };
    auto writeB = [&]() {
        #pragma unroll
        for (int j = 0; j < 4; j++) {
            int nn = n4 + j;
            unsigned u;
            asm("v_cvt_pk_bf16_f32 %0, %1, %2" : "=v"(u)
                : "v"(((const float*)&r0)[j]), "v"(((const float*)&r1)[j]));
            int kx = kb ^ (((nn >> 3) & 1) << 3);
            *(unsigned*)&Bs[nn*BKP + kx] = u;
        }
    };
    int sr0 = tid >> 2, sc0 = (tid & 3) ^ ((sr0 >> 1) & 3);
    int sr1 = 128 + sr0, sc1 = (tid & 3) ^ ((sr1 >> 1) & 3);
    auto stageA = [&](int p, int t) {
        int k0 = t * 32;
        char* dst = (char*)As[p];
        gl_lds16(xga + (size_t)sr0 * DMODEL + k0 + sc0 * 8, dst + tid*16);
        gl_lds16(xga + (size_t)sr1 * DMODEL + k0 + sc1 * 8, dst + 8192 + tid*16);
    };

    const int NT = DMODEL / 32;
    issueB(0);
    stageA(0, 0);
    if (mrows >= 256) {
        for (int t = 0; t < NT; t++) {
            int p = t & 1;
            writeB();
            __syncthreads();
            if (t + 1 < NT) { issueB(t + 1); stageA(p ^ 1, t + 1); }
            bf16x8 a[4], b[4];
            #pragma unroll
            for (int ms = 0; ms < 4; ms++) {
                int r = wm + ms*16 + lrow;
                int c = lkg ^ ((r >> 1) & 3);
                a[ms] = *(const bf16x8*)&As[p][r*32 + c*8];
            }
            #pragma unroll
            for (int ni = 0; ni < 4; ni++) {
                int nb = wn + ni*16 + lrow;
                int ks = (lkg*8) ^ (((nb >> 3) & 1) << 3);
                b[ni] = *(const bf16x8*)&Bs[nb*BKP + ks];
            }
            #pragma unroll
            for (int ms = 0; ms < 4; ms++)
              #pragma unroll
              for (int ni = 0; ni < 4; ni++)
                acc[ms][ni] = __builtin_amdgcn_mfma_f32_16x16x32_bf16(a[ms], b[ni], acc[ms][ni], 0, 0, 0);
            __syncthreads();
        }
    } else {
        bool act0 = wm +  0 < mrows;
        bool act1 = wm + 16 < mrows;
        bool act2 = wm + 32 < mrows;
        bool act3 = wm + 48 < mrows;
        for (int t = 0; t < NT; t++) {
            int p = t & 1;
            writeB();
            __syncthreads();
            if (t + 1 < NT) { issueB(t + 1); stageA(p ^ 1, t + 1); }
            bf16x8 b[4];
            #pragma unroll
            for (int ni = 0; ni < 4; ni++) {
                int nb = wn + ni*16 + lrow;
                int ks = (lkg*8) ^ (((nb >> 3) & 1) << 3);
                b[ni] = *(const bf16x8*)&Bs[nb*BKP + ks];
            }
            #define FRAG1(MS, ACT)                                              \
            if (ACT) {                                                          \
                int r = wm + MS*16 + lrow;                                      \
                int c = lkg ^ ((r >> 1) & 3);                                   \
                bf16x8 a = *(const bf16x8*)&As[p][r*32 + c*8];                  \
                acc[MS][0] = __builtin_amdgcn_mfma_f32_16x16x32_bf16(a, b[0], acc[MS][0], 0, 0, 0); \
                acc[MS][1] = __builtin_amdgcn_mfma_f32_16x16x32_bf16(a, b[1], acc[MS][1], 0, 0, 0); \
                acc[MS][2] = __builtin_amdgcn_mfma_f32_16x16x32_bf16(a, b[2], acc[MS][2], 0, 0, 0); \
                acc[MS][3] = __builtin_amdgcn_mfma_f32_16x16x32_bf16(a, b[3], acc[MS][3], 0, 0, 0); \
            }
            FRAG1(0, act0) FRAG1(1, act1) FRAG1(2, act2) FRAG1(3, act3)
            #undef FRAG1
            __syncthreads();
        }
    }

    #pragma unroll
    for (int ms = 0; ms < 4; ms++) {
        #pragma unroll
        for (int ni = 0; ni < 4; ni++) {
            int n = n0 + wn + ni*16 + lrow;
            float bias = b1[e*DFF + n];
            #pragma unroll
            for (int r = 0; r < 4; r++) {
                int ml = wm + ms*16 + lkg*4 + r;
                if (ml < mrows) {
                    float u = acc[ms][ni][r] + bias;
                    float t2 = 0.7978845608f * (u + 0.044715f * u * u * u);
                    float sg = 1.f / (1.f + __expf(-2.f * t2));
                    hbuf[(size_t)(slotbase + ml) * DFF + n] = f2bf(u * sg);
                }
            }
        }
    }
}

// ---------------- GEMM2: y[slot] = gate*(h @ w2 + b2) — M=192, issue-late ----
__global__ __launch_bounds__(512) void k_ffn2(
    const unsigned short* __restrict__ hbuf, const float* __restrict__ w2,
    const float* __restrict__ b2, const int* __restrict__ offsets,
    const float* __restrict__ slot_gate, float* __restrict__ y)
{
    int bid = blockIdx.x;
    int xcd = bid & 7, s = bid >> 3;           // s in [0,72)
    int eg = s / 24, rem = s % 24;             // 24 = 8 nx * 3 mt
    int nx = rem / 3, mt = rem % 3;
    int e = eg * 8 + xcd;

    int base = offsets[e], ne = offsets[e+1] - base;
    if (mt * 192 >= ne) return;
    int n0 = nx * 128;
    int slotbase = base + mt * 192;

    __shared__ unsigned short As[2][192*32];
    __shared__ unsigned short Bs[128*BKP];
    __shared__ float gat[192];

    int tid = threadIdx.x, l = tid & 63, wv = tid >> 6;
    if (tid < 192)
        gat[tid] = (mt*192 + tid < ne) ? slot_gate[slotbase + tid] : 0.f;

    int wm = (wv >> 1) * 48, wn = (wv & 1) * 64;
    int lrow = l & 15, lkg = l >> 4;

    f32x4 acc[3][4];
    #pragma unroll
    for (int i = 0; i < 3; i++)
      #pragma unroll
      for (int j = 0; j < 4; j++)
        acc[i][j] = (f32x4){0.f, 0.f, 0.f, 0.f};

    const unsigned short* hba = hbuf + (size_t)slotbase * DFF;
    const float* w2e = w2 + (size_t)e * DFF * DMODEL + n0;

    int n4 = (tid & 31) * 4, kb = (tid >> 5) * 2;
    float4 r0, r1;
    auto issueB = [&](int t) {
        const float* p = w2e + (size_t)(t*32 + kb) * DMODEL + n4;
        r0 = *(const float4*)p;
        r1 = *(const float4*)(p + DMODEL);
    };
    auto writeB = [&]() {
        #pragma unroll
        for (int j = 0; j < 4; j++) {
            int nn = n4 + j;
            unsigned u;
            asm("v_cvt_pk_bf16_f32 %0, %1, %2" : "=v"(u)
                : "v"(((const float*)&r0)[j]), "v"(((const float*)&r1)[j]));
            int kx = kb ^ (((nn >> 3) & 1) << 3);
            *(unsigned*)&Bs[nn*BKP + kx] = u;
        }
    };
    int sr0 = tid >> 2, sc0 = (tid & 3) ^ ((sr0 >> 1) & 3);
    int su1 = 512 + tid;
    int sr1 = su1 >> 2, sc1 = (su1 & 3) ^ ((sr1 >> 1) & 3);
    auto stageA = [&](int p, int t) {
        int k0 = t * 32;
        char* dst = (char*)As[p];
        gl_lds16(hba + (size_t)sr0 * DFF + k0 + sc0 * 8, dst + tid*16);
        if (tid < 256)
            gl_lds16(hba + (size_t)sr1 * DFF + k0 + sc1 * 8, dst + su1*16);
    };

    const int NT = DFF / 32;
    issueB(0);
    stageA(0, 0);
    for (int t = 0; t < NT; t++) {
        int p = t & 1;
        writeB();
        __syncthreads();
        if (t + 1 < NT) { issueB(t + 1); stageA(p ^ 1, t + 1); }
        bf16x8 a[3], b[4];
        #pragma unroll
        for (int ms = 0; ms < 3; ms++) {
            int r = wm + ms*16 + lrow;
            int c = lkg ^ ((r >> 1) & 3);
            a[ms] = *(const bf16x8*)&As[p][r*32 + c*8];
        }
        #pragma unroll
        for (int ni = 0; ni < 4; ni++) {
            int nb = wn + ni*16 + lrow;
            int ks = (lkg*8) ^ (((nb >> 3) & 1) << 3);
            b[ni] = *(const bf16x8*)&Bs[nb*BKP + ks];
        }
        #pragma unroll
        for (int ms = 0; ms < 3; ms++)
          #pragma unroll
          for (int ni = 0; ni < 4; ni++)
            acc[ms][ni] = __builtin_amdgcn_mfma_f32_16x16x32_bf16(a[ms], b[ni], acc[ms][ni], 0, 0, 0);
        __syncthreads();
    }

    #pragma unroll
    for (int ms = 0; ms < 3; ms++) {
        #pragma unroll
        for (int ni = 0; ni < 4; ni++) {
            int n = n0 + wn + ni*16 + lrow;
            float bias = b2[e*DMODEL + n];
            #pragma unroll
            for (int r = 0; r < 4; r++) {
                int ml = wm + ms*16 + lkg*4 + r;
                if (mt*192 + ml < ne) {
                    y[(size_t)(slotbase + ml) * DMODEL + n] = gat[ml] * (acc[ms][ni][r] + bias);
                }
            }
        }
    }
}

// ---------------- combine: out[t] = y[slot0] + y[slot1] ----------------
__global__ __launch_bounds__(256) void k_combine(
    const float* __restrict__ y, const int* __restrict__ slot_of,
    float* __restrict__ out)
{
    int t = blockIdx.x, tid = threadIdx.x;
    int s0 = slot_of[t*2], s1 = slot_of[t*2+1];
    float4 a = ((const float4*)(y + (size_t)s0 * DMODEL))[tid];
    float4 b = ((const float4*)(y + (size_t)s1 * DMODEL))[tid];
    float4 o = {a.x+b.x, a.y+b.y, a.z+b.z, a.w+b.w};
    ((float4*)(out + (size_t)t * DMODEL))[tid] = o;
}

extern "C" void kernel_launch(void* const* d_in, const int* in_sizes, int n_in,
                              void* d_out, int out_size, void* d_ws, size_t ws_size,
                              hipStream_t stream) {
    const float* x  = (const float*)d_in[0];
    const float* gw = (const float*)d_in[1];
    const float* gb = (const float*)d_in[2];
    const float* w1 = (const float*)d_in[3];
    const float* b1 = (const float*)d_in[4];
    const float* w2 = (const float*)d_in[5];
    const float* b2 = (const float*)d_in[6];
    float* out = (float*)d_out;
    char* ws = (char*)d_ws;

    int*   counts     = (int*)(ws + 0);
    int*   counts2    = (int*)(ws + 128);
    int*   offsets    = (int*)(ws + 256);
    int*   topk_e     = (int*)(ws + 512);
    float* topk_g     = (float*)(ws + 33280);
    int*   slot_token = (int*)(ws + 66048);
    float* slot_gate  = (float*)(ws + 99328);
    int*   slot_of    = (int*)(ws + 132608);
    // xg (bf16, ~18MB padded) and y (f32, ~34MB) share region: disjoint lifetimes
    unsigned short* xg = (unsigned short*)(ws + 1048576);
    float*          y  = (float*)(ws + 1048576);
    unsigned short* hbuf = (unsigned short*)(ws + 35651584);  // 8768 x 4096 bf16 (padded)

    k_zero<<<1, 128, 0, stream>>>((int*)ws);

    k_gate<<<T_TOKENS/8, 256, 0, stream>>>(x, gw, gb, topk_e, topk_g, counts);
    k_scan<<<1, 64, 0, stream>>>(counts, offsets);
    k_assign<<<NSLOTS/256, 256, 0, stream>>>(topk_e, topk_g, offsets, counts2,
                                             slot_token, slot_gate, slot_of);
    k_xgather<<<NSLOTS*128/256, 256, 0, stream>>>(x, slot_token, xg);

    k_ffn1<<<dim3(8 * 192), 512, 0, stream>>>(xg, w1, b1, offsets, hbuf);

    k_ffn2<<<dim3(8 * 72), 512, 0, stream>>>(hbuf, w2, b2, offsets, slot_gate, y);

    k_combine<<<T_TOKENS, 256, 0, stream>>>(y, slot_of, out);
}

// Round 18
// 422.162 us; speedup vs baseline: 1.0827x; 1.0827x over previous
//
#include <hip/hip_runtime.h>
#include <hip/hip_bf16.h>
#include <math.h>

#define T_TOKENS 4096
#define DMODEL 1024
#define DFF 4096
#define NEXP 24
#define NSLOTS 8192
#define BKP 40   // Bs row stride in shorts (80B, 16B-aligned)

typedef __attribute__((ext_vector_type(8))) short bf16x8;
typedef __attribute__((ext_vector_type(4))) float f32x4;
typedef __attribute__((ext_vector_type(8))) unsigned short us8;

static __device__ __forceinline__ unsigned short f2bf(float f) {
    union { float f; unsigned u; } v; v.f = f;
    unsigned r = v.u + 0x7fffu + ((v.u >> 16) & 1u);
    return (unsigned short)(r >> 16);
}

typedef const __attribute__((address_space(1))) void gvoid_t;
typedef __attribute__((address_space(3))) void lvoid_t;
static __device__ __forceinline__ void gl_lds16(const void* g, void* l) {
    __builtin_amdgcn_global_load_lds((gvoid_t*)g, (lvoid_t*)l, 16, 0, 0);
}

// ---------------- zero the control block ----------------
__global__ void k_zero(int* __restrict__ p) { p[threadIdx.x] = 0; }

// ---------------- gating: block = 8 tokens x 32 lanes (lane = expert) --------
__global__ __launch_bounds__(256) void k_gate(
    const float* __restrict__ x, const float* __restrict__ gw,
    const float* __restrict__ gb, int* __restrict__ topk_e,
    float* __restrict__ topk_g, int* __restrict__ counts)
{
    __shared__ float xs[8][1024];
    __shared__ float sc[8][24];
    __shared__ int lcnt[24];
    int tid = threadIdx.x;
    int t0 = blockIdx.x * 8;
    #pragma unroll
    for (int i = 0; i < 8; i++) {
        int idx = tid + 256*i;
        int r = idx >> 8, c4 = (idx & 255) * 4;
        *(float4*)&xs[r][c4] = *(const float4*)(x + (size_t)(t0+r)*DMODEL + c4);
    }
    if (tid < 24) lcnt[tid] = 0;
    __syncthreads();

    int tok = tid >> 5, e = tid & 31;
    if (e < NEXP) {
        float s0=0.f, s1=0.f, s2=0.f, s3=0.f;
        #pragma unroll 4
        for (int d = 0; d < DMODEL; d += 4) {
            s0 += xs[tok][d]   * gw[(d  )*NEXP + e];
            s1 += xs[tok][d+1] * gw[(d+1)*NEXP + e];
            s2 += xs[tok][d+2] * gw[(d+2)*NEXP + e];
            s3 += xs[tok][d+3] * gw[(d+3)*NEXP + e];
        }
        sc[tok][e] = (s0+s1)+(s2+s3) + gb[e];
    }
    __syncthreads();

    if (tid < 8) {
        int t = t0 + tid;
        float v0=-1e30f, v1=-1e30f; int i0=0, i1=0;
        #pragma unroll
        for (int ee = 0; ee < NEXP; ee++) {
            float s = sc[tid][ee];
            if (s > v0) { v1=v0; i1=i0; v0=s; i0=ee; }
            else if (s > v1) { v1=s; i1=ee; }
        }
        float e1 = expf(v1 - v0);
        float g0 = 1.f/(1.f+e1), g1 = e1/(1.f+e1);
        topk_e[t*2]=i0; topk_e[t*2+1]=i1;
        topk_g[t*2]=g0; topk_g[t*2+1]=g1;
        atomicAdd(&lcnt[i0], 1); atomicAdd(&lcnt[i1], 1);
    }
    __syncthreads();
    if (tid < NEXP && lcnt[tid]) atomicAdd(&counts[tid], lcnt[tid]);
}

__global__ void k_scan(const int* __restrict__ counts, int* __restrict__ offsets) {
    if (threadIdx.x == 0) {
        int run = 0;
        for (int e = 0; e < NEXP; e++) { offsets[e] = run; run += counts[e]; }
        offsets[NEXP] = run;
    }
}

__global__ __launch_bounds__(256) void k_assign(
    const int* __restrict__ topk_e, const float* __restrict__ topk_g,
    const int* __restrict__ offsets, int* __restrict__ counts2,
    int* __restrict__ slot_token, float* __restrict__ slot_gate,
    int* __restrict__ slot_of)
{
    int idx = blockIdx.x * 256 + threadIdx.x;
    if (idx >= NSLOTS) return;
    int e = topk_e[idx];
    int pos = offsets[e] + atomicAdd(&counts2[e], 1);
    slot_token[pos] = idx >> 1;
    slot_gate[pos] = topk_g[idx];
    slot_of[idx] = pos;
}

// ---------------- gather x -> xg[slot][DMODEL] bf16 ----------------
__global__ __launch_bounds__(256) void k_xgather(
    const float* __restrict__ x, const int* __restrict__ slot_token,
    unsigned short* __restrict__ xg)
{
    int idx = blockIdx.x * 256 + threadIdx.x;
    int slot = idx >> 7, c8 = (idx & 127) * 8;
    int tok = slot_token[slot];
    const float4* p = (const float4*)(x + (size_t)tok * DMODEL + c8);
    float4 v0 = p[0], v1 = p[1];
    us8 o;
    o[0]=f2bf(v0.x); o[1]=f2bf(v0.y); o[2]=f2bf(v0.z); o[3]=f2bf(v0.w);
    o[4]=f2bf(v1.x); o[5]=f2bf(v1.y); o[6]=f2bf(v1.z); o[7]=f2bf(v1.w);
    *(us8*)(xg + (size_t)slot * DMODEL + c8) = o;
}

// ---------------- GEMM1: h = gelu(xg @ w1 + b1) ------------------------------
// M=256, N=128, BK=32, 512 thr (8 waves 4m x 2n, wave-tile 64x64, acc 4x4).
// Block-uniform dual path: full tiles run the R13 body verbatim; partial
// tiles (mrows<256) run a fragment-guarded body.
__global__ __launch_bounds__(512) void k_ffn1(
    const unsigned short* __restrict__ xg, const float* __restrict__ w1,
    const float* __restrict__ b1, const int* __restrict__ offsets,
    unsigned short* __restrict__ hbuf)
{
    int bid = blockIdx.x;
    int xcd = bid & 7, s = bid >> 3;           // s in [0,192)
    int eg = s >> 6, rem = s & 63;             // 64 = 32 nx * 2 mt
    int nx = rem >> 1, mt = rem & 1;
    int e = eg * 8 + xcd;

    int base = offsets[e], ne = offsets[e+1] - base;
    if (mt * 256 >= ne) return;
    int n0 = nx * 128;
    int slotbase = base + mt * 256;
    int mrows = ne - mt * 256;

    __shared__ unsigned short As[2][256*32];
    __shared__ unsigned short Bs[128*BKP];

    int tid = threadIdx.x, l = tid & 63, wv = tid >> 6;
    int wm = (wv >> 1) * 64, wn = (wv & 1) * 64;
    int lrow = l & 15, lkg = l >> 4;

    f32x4 acc[4][4];
    #pragma unroll
    for (int i = 0; i < 4; i++)
      #pragma unroll
      for (int j = 0; j < 4; j++)
        acc[i][j] = (f32x4){0.f, 0.f, 0.f, 0.f};

    const unsigned short* xga = xg + (size_t)slotbase * DMODEL;
    const float* w1e = w1 + (size_t)e * DMODEL * DFF + n0;

    int n4 = (tid & 31) * 4, kb = (tid >> 5) * 2;   // 2k x 4n block per thread
    float4 r0, r1;
    auto issueB = [&](int t) {
        const float* p = w1e + (size_t)(t*32 + kb) * DFF + n4;
        r0 = *(const float4*)p;
        r1 = *(const float4*)(p + DFF);
    };
    auto writeB = [&]() {
        #pragma unroll
        for (int j = 0; j < 4; j++) {
            int nn = n4 + j;
            unsigned u;
            asm("v_cvt_pk_bf16_f32 %0, %1, %2" : "=v"(u)
                : "v"(((const float*)&r0)[j]), "v"(((const float*)&r1)[j]));
            int kx = kb ^ (((nn >> 3) & 1) << 3);
            *(unsigned*)&Bs[nn*BKP + kx] = u;
        }
    };
    int sr0 = tid >> 2, sc0 = (tid & 3) ^ ((sr0 >> 1) & 3);
    int sr1 = 128 + sr0, sc1 = (tid & 3) ^ ((sr1 >> 1) & 3);
    auto stageA = [&](int p, int t) {
        int k0 = t * 32;
        char* dst = (char*)As[p];
        gl_lds16(xga + (size_t)sr0 * DMODEL + k0 + sc0 * 8, dst + tid*16);
        gl_lds16(xga + (size_t)sr1 * DMODEL + k0 + sc1 * 8, dst + 8192 + tid*16);
    };

    const int NT = DMODEL / 32;
    issueB(0);
    stageA(0, 0);
    if (mrows >= 256) {
        // ---- full-tile path ----
        for (int t = 0; t < NT; t++) {
            int p = t & 1;
            writeB();
            if (t + 1 < NT) issueB(t + 1);
            __syncthreads();
            if (t + 1 < NT) stageA(p ^ 1, t + 1);
            bf16x8 a[4], b[4];
            #pragma unroll
            for (int ms = 0; ms < 4; ms++) {
                int r = wm + ms*16 + lrow;
                int c = lkg ^ ((r >> 1) & 3);
                a[ms] = *(const bf16x8*)&As[p][r*32 + c*8];
            }
            #pragma unroll
            for (int ni = 0; ni < 4; ni++) {
                int nb = wn + ni*16 + lrow;
                int ks = (lkg*8) ^ (((nb >> 3) & 1) << 3);
                b[ni] = *(const bf16x8*)&Bs[nb*BKP + ks];
            }
            #pragma unroll
            for (int ms = 0; ms < 4; ms++)
              #pragma unroll
              for (int ni = 0; ni < 4; ni++)
                acc[ms][ni] = __builtin_amdgcn_mfma_f32_16x16x32_bf16(a[ms], b[ni], acc[ms][ni], 0, 0, 0);
            __syncthreads();
        }
    } else {
        // ---- partial-tile path: fragment-guarded ----
        bool act0 = wm +  0 < mrows;
        bool act1 = wm + 16 < mrows;
        bool act2 = wm + 32 < mrows;
        bool act3 = wm + 48 < mrows;
        for (int t = 0; t < NT; t++) {
            int p = t & 1;
            writeB();
            if (t + 1 < NT) issueB(t + 1);
            __syncthreads();
            if (t + 1 < NT) stageA(p ^ 1, t + 1);
            bf16x8 b[4];
            #pragma unroll
            for (int ni = 0; ni < 4; ni++) {
                int nb = wn + ni*16 + lrow;
                int ks = (lkg*8) ^ (((nb >> 3) & 1) << 3);
                b[ni] = *(const bf16x8*)&Bs[nb*BKP + ks];
            }
            #define FRAG1(MS, ACT)                                              \
            if (ACT) {                                                          \
                int r = wm + MS*16 + lrow;                                      \
                int c = lkg ^ ((r >> 1) & 3);                                   \
                bf16x8 a = *(const bf16x8*)&As[p][r*32 + c*8];                  \
                acc[MS][0] = __builtin_amdgcn_mfma_f32_16x16x32_bf16(a, b[0], acc[MS][0], 0, 0, 0); \
                acc[MS][1] = __builtin_amdgcn_mfma_f32_16x16x32_bf16(a, b[1], acc[MS][1], 0, 0, 0); \
                acc[MS][2] = __builtin_amdgcn_mfma_f32_16x16x32_bf16(a, b[2], acc[MS][2], 0, 0, 0); \
                acc[MS][3] = __builtin_amdgcn_mfma_f32_16x16x32_bf16(a, b[3], acc[MS][3], 0, 0, 0); \
            }
            FRAG1(0, act0) FRAG1(1, act1) FRAG1(2, act2) FRAG1(3, act3)
            #undef FRAG1
            __syncthreads();
        }
    }

    #pragma unroll
    for (int ms = 0; ms < 4; ms++) {
        #pragma unroll
        for (int ni = 0; ni < 4; ni++) {
            int n = n0 + wn + ni*16 + lrow;
            float bias = b1[e*DFF + n];
            #pragma unroll
            for (int r = 0; r < 4; r++) {
                int ml = wm + ms*16 + lkg*4 + r;
                if (ml < mrows) {
                    float u = acc[ms][ni][r] + bias;
                    float t2 = 0.7978845608f * (u + 0.044715f * u * u * u);
                    float sg = 1.f / (1.f + __expf(-2.f * t2));
                    hbuf[(size_t)(slotbase + ml) * DFF + n] = f2bf(u * sg);
                }
            }
        }
    }
}

// ---------------- GEMM2: y[slot] = gate*(h @ w2 + b2) — M=192 ---------------
__global__ __launch_bounds__(512) void k_ffn2(
    const unsigned short* __restrict__ hbuf, const float* __restrict__ w2,
    const float* __restrict__ b2, const int* __restrict__ offsets,
    const float* __restrict__ slot_gate, float* __restrict__ y)
{
    int bid = blockIdx.x;
    int xcd = bid & 7, s = bid >> 3;           // s in [0,72)
    int eg = s / 24, rem = s % 24;             // 24 = 8 nx * 3 mt
    int nx = rem / 3, mt = rem % 3;
    int e = eg * 8 + xcd;

    int base = offsets[e], ne = offsets[e+1] - base;
    if (mt * 192 >= ne) return;
    int n0 = nx * 128;
    int slotbase = base + mt * 192;

    __shared__ unsigned short As[2][192*32];
    __shared__ unsigned short Bs[128*BKP];
    __shared__ float gat[192];

    int tid = threadIdx.x, l = tid & 63, wv = tid >> 6;
    if (tid < 192)
        gat[tid] = (mt*192 + tid < ne) ? slot_gate[slotbase + tid] : 0.f;

    int wm = (wv >> 1) * 48, wn = (wv & 1) * 64;
    int lrow = l & 15, lkg = l >> 4;

    f32x4 acc[3][4];
    #pragma unroll
    for (int i = 0; i < 3; i++)
      #pragma unroll
      for (int j = 0; j < 4; j++)
        acc[i][j] = (f32x4){0.f, 0.f, 0.f, 0.f};

    const unsigned short* hba = hbuf + (size_t)slotbase * DFF;
    const float* w2e = w2 + (size_t)e * DFF * DMODEL + n0;

    int n4 = (tid & 31) * 4, kb = (tid >> 5) * 2;
    float4 r0, r1;
    auto issueB = [&](int t) {
        const float* p = w2e + (size_t)(t*32 + kb) * DMODEL + n4;
        r0 = *(const float4*)p;
        r1 = *(const float4*)(p + DMODEL);
    };
    auto writeB = [&]() {
        #pragma unroll
        for (int j = 0; j < 4; j++) {
            int nn = n4 + j;
            unsigned u;
            asm("v_cvt_pk_bf16_f32 %0, %1, %2" : "=v"(u)
                : "v"(((const float*)&r0)[j]), "v"(((const float*)&r1)[j]));
            int kx = kb ^ (((nn >> 3) & 1) << 3);
            *(unsigned*)&Bs[nn*BKP + kx] = u;
        }
    };
    int sr0 = tid >> 2, sc0 = (tid & 3) ^ ((sr0 >> 1) & 3);
    int su1 = 512 + tid;
    int sr1 = su1 >> 2, sc1 = (su1 & 3) ^ ((sr1 >> 1) & 3);
    auto stageA = [&](int p, int t) {
        int k0 = t * 32;
        char* dst = (char*)As[p];
        gl_lds16(hba + (size_t)sr0 * DFF + k0 + sc0 * 8, dst + tid*16);
        if (tid < 256)
            gl_lds16(hba + (size_t)sr1 * DFF + k0 + sc1 * 8, dst + su1*16);
    };

    const int NT = DFF / 32;
    issueB(0);
    stageA(0, 0);
    for (int t = 0; t < NT; t++) {
        int p = t & 1;
        writeB();
        if (t + 1 < NT) issueB(t + 1);
        __syncthreads();
        if (t + 1 < NT) stageA(p ^ 1, t + 1);
        bf16x8 a[3], b[4];
        #pragma unroll
        for (int ms = 0; ms < 3; ms++) {
            int r = wm + ms*16 + lrow;
            int c = lkg ^ ((r >> 1) & 3);
            a[ms] = *(const bf16x8*)&As[p][r*32 + c*8];
        }
        #pragma unroll
        for (int ni = 0; ni < 4; ni++) {
            int nb = wn + ni*16 + lrow;
            int ks = (lkg*8) ^ (((nb >> 3) & 1) << 3);
            b[ni] = *(const bf16x8*)&Bs[nb*BKP + ks];
        }
        #pragma unroll
        for (int ms = 0; ms < 3; ms++)
          #pragma unroll
          for (int ni = 0; ni < 4; ni++)
            acc[ms][ni] = __builtin_amdgcn_mfma_f32_16x16x32_bf16(a[ms], b[ni], acc[ms][ni], 0, 0, 0);
        __syncthreads();
    }

    #pragma unroll
    for (int ms = 0; ms < 3; ms++) {
        #pragma unroll
        for (int ni = 0; ni < 4; ni++) {
            int n = n0 + wn + ni*16 + lrow;
            float bias = b2[e*DMODEL + n];
            #pragma unroll
            for (int r = 0; r < 4; r++) {
                int ml = wm + ms*16 + lkg*4 + r;
                if (mt*192 + ml < ne) {
                    y[(size_t)(slotbase + ml) * DMODEL + n] = gat[ml] * (acc[ms][ni][r] + bias);
                }
            }
        }
    }
}

// ---------------- combine: out[t] = y[slot0] + y[slot1] ----------------
__global__ __launch_bounds__(256) void k_combine(
    const float* __restrict__ y, const int* __restrict__ slot_of,
    float* __restrict__ out)
{
    int t = blockIdx.x, tid = threadIdx.x;
    int s0 = slot_of[t*2], s1 = slot_of[t*2+1];
    float4 a = ((const float4*)(y + (size_t)s0 * DMODEL))[tid];
    float4 b = ((const float4*)(y + (size_t)s1 * DMODEL))[tid];
    float4 o = {a.x+b.x, a.y+b.y, a.z+b.z, a.w+b.w};
    ((float4*)(out + (size_t)t * DMODEL))[tid] = o;
}

extern "C" void kernel_launch(void* const* d_in, const int* in_sizes, int n_in,
                              void* d_out, int out_size, void* d_ws, size_t ws_size,
                              hipStream_t stream) {
    const float* x  = (const float*)d_in[0];
    const float* gw = (const float*)d_in[1];
    const float* gb = (const float*)d_in[2];
    const float* w1 = (const float*)d_in[3];
    const float* b1 = (const float*)d_in[4];
    const float* w2 = (const float*)d_in[5];
    const float* b2 = (const float*)d_in[6];
    float* out = (float*)d_out;
    char* ws = (char*)d_ws;

    int*   counts     = (int*)(ws + 0);
    int*   counts2    = (int*)(ws + 128);
    int*   offsets    = (int*)(ws + 256);
    int*   topk_e     = (int*)(ws + 512);
    float* topk_g     = (float*)(ws + 33280);
    int*   slot_token = (int*)(ws + 66048);
    float* slot_gate  = (float*)(ws + 99328);
    int*   slot_of    = (int*)(ws + 132608);
    // xg (bf16, ~18MB padded) and y (f32, ~34MB) share region: disjoint lifetimes
    unsigned short* xg = (unsigned short*)(ws + 1048576);
    float*          y  = (float*)(ws + 1048576);
    unsigned short* hbuf = (unsigned short*)(ws + 35651584);  // 8768 x 4096 bf16 (padded)

    k_zero<<<1, 128, 0, stream>>>((int*)ws);

    k_gate<<<T_TOKENS/8, 256, 0, stream>>>(x, gw, gb, topk_e, topk_g, counts);
    k_scan<<<1, 64, 0, stream>>>(counts, offsets);
    k_assign<<<NSLOTS/256, 256, 0, stream>>>(topk_e, topk_g, offsets, counts2,
                                             slot_token, slot_gate, slot_of);
    k_xgather<<<NSLOTS*128/256, 256, 0, stream>>>(x, slot_token, xg);

    k_ffn1<<<dim3(8 * 192), 512, 0, stream>>>(xg, w1, b1, offsets, hbuf);

    k_ffn2<<<dim3(8 * 72), 512, 0, stream>>>(hbuf, w2, b2, offsets, slot_gate, y);

    k_combine<<<T_TOKENS, 256, 0, stream>>>(y, slot_of, out);
}